// Round 5
// baseline (361.227 us; speedup 1.0000x reference)
//
#include <hip/hip_runtime.h>
#include <math.h>

#define CC 2048   // channels (C)
#define DD 256    // reduced channels (D)
#define PP 4096   // HW = 64*64
#define NB 4      // batch

typedef float f32x4 __attribute__((ext_vector_type(4)));
typedef __bf16 bfrag __attribute__((ext_vector_type(8)));

#define AS1(p) ((const __attribute__((address_space(1))) void*)(p))
#define AS3(p) ((__attribute__((address_space(3))) void*)(p))

__device__ __forceinline__ unsigned short f2bf(float f) {
    unsigned int u = __float_as_uint(f);
    u = (u + 0x7fffu + ((u >> 16) & 1u)) >> 16;
    return (unsigned short)u;
}

// ---------------- fused: x transpose+cvt (z<NB) and w3 cvt (z==NB) ----------------
__global__ __launch_bounds__(256) void prep(const float* __restrict__ x, unsigned short* __restrict__ xT,
                                            const float* __restrict__ w3, unsigned short* __restrict__ w3b) {
    const int t = threadIdx.x;
    if (blockIdx.z == NB) {
        int bid = blockIdx.y * 64 + blockIdx.x;   // 0..2047
        int base = (bid * 256 + t) * 8;
#pragma unroll
        for (int j = 0; j < 2; ++j) {
            float4 v = *(const float4*)(w3 + base + j * 4);
            ushort4 r;
            r.x = f2bf(v.x); r.y = f2bf(v.y); r.z = f2bf(v.z); r.w = f2bf(v.w);
            *(ushort4*)(w3b + base + j * 4) = r;
        }
        return;
    }
    __shared__ float tile[64 * 64];
    const int n  = blockIdx.z;
    const int c0 = blockIdx.y * 64;
    const int p0 = blockIdx.x * 64;
    const float* xn = x + (size_t)n * CC * PP;
    {
        const int cl = t >> 4;
        const int g  = t & 15;
        const int pl = g * 4;
#pragma unroll
        for (int ps = 0; ps < 4; ++ps) {
            const int c = cl + ps * 16;
            float4 v = *(const float4*)(xn + (size_t)(c0 + c) * PP + p0 + pl);
            const int gs = g ^ (c >> 2);
            *(float4*)(tile + c * 64 + gs * 4) = v;
        }
    }
    __syncthreads();
    unsigned short* xTn = xT + (size_t)n * PP * CC;
    {
        const int pl2 = t >> 4;
        const int cq  = t & 15;
        const int c4  = cq * 4;
#pragma unroll
        for (int ps = 0; ps < 4; ++ps) {
            const int p  = pl2 + ps * 16;
            const int gs2 = (p >> 2) ^ cq;
            const int base = gs2 * 4 + (p & 3);
            ushort4 r;
            r.x = f2bf(tile[(c4 + 0) * 64 + base]);
            r.y = f2bf(tile[(c4 + 1) * 64 + base]);
            r.z = f2bf(tile[(c4 + 2) * 64 + base]);
            r.w = f2bf(tile[(c4 + 3) * 64 + base]);
            *(ushort4*)(xTn + (size_t)(p0 + p) * CC + c0 + c4) = r;
        }
    }
}

// ---------------- assembly = relu(w3 . x + b3) ----------------
// 256x256 tile, BK=64, 8 waves (2M x 4N), wave tile 128x64 via 8x4 of
// mfma_f32_16x16x32_bf16, conflict-free chunk-XOR LDS (round-3: verified
// 0 bank conflicts). Round-5: round-3's exact 8-barrier/4-phase rhythm,
// ONE change — each ds_read group is issued one phase before its consuming
// MFMA cluster, gated by counted lgkmcnt (the true m201 "4 or 8 reads per
// phase" schedule). Round-3's per-phase lgkm(0) serialized LDS vs MFMA
// (measured per-tile 4820cyc = 2480 MFMA + 2300 LDS serial sum); with
// phase-lead reads the LDS pipe serves cluster i+1 during cluster i.
//   p1: issue bN23(kt)[4]   ; stage A(kt+1)h0 ; BARR ; WLG(4) ; Q1 = a0-3 x bn01
//   p2: issue a4-7(kt)[8]   ; stage A(kt+1)h1 ; BARR ; WLG(8) ; Q2 = a0-3 x bn23
//   p3: stage B(kt+2)h0 ; WVM(2) ; BARR ; issue a0-3(kt+1)[8] ; WLG(8) ; Q3 = a4-7 x bn23
//   p4: stage B(kt+2)h1 ; BARR ; Q4 = a4-7 x bn01 ; issue bN01(kt+1)[4] ; BARR
// Derived-wait audit (outstanding -> retired at each gate, steady state):
//   p1 WLG(4): 16 -> drains a0-3(kt)+bN01(kt) (issued prev p3/p4), leaves bn23
//   p2 WLG(8): 12 -> drains bn23, leaves a4-7
//   p3 WVM(2): 10 -> retires A(kt+1)h0/h1 + B(kt+1)h0/h1, keeps B(kt+2)h0;
//              barrier after = cross-wave landing guarantee for the a0-3(kt+1)
//              and p4 bN01(kt+1) ds_reads that follow
//   p3 WLG(8): 16 -> drains a4-7, leaves a0-3(kt+1)
//   p4: no lgkm gate needed (Q4 operands drained at p1/p3)
// STG-overwrite hazards: every STG targets a region whose last reader gate
// (WLG) is followed by a barrier that precedes the STG (A: p3-end barrier of
// prev tile; Bh0/h1: p2-end barrier of this tile). vmcnt never 0 in main
// loop. B register set reused in-place (reads issued after Q4) - no ping-pong,
// 24 frags total = round-4's proven register budget.
// NO XCD swizzle (round-1: natural order keeps B L2-resident, 99 vs 270 MB).
__global__ __launch_bounds__(512, 2) void gemm_assembly(
    const unsigned short* __restrict__ w3b,
    const unsigned short* __restrict__ xT,
    const float* __restrict__ b3,
    float* __restrict__ out)
{
    // layout (bytes): A: buf*32768 + half*16384 + row*128 ; B: +65536 same
    __shared__ __align__(16) char sm[131072];

    const int t    = threadIdx.x;
    const int wave = t >> 6;
    const int lane = t & 63;
    const int swz  = lane & 7;

    const int p0 = blockIdx.x << 8;
    const int m0 = blockIdx.y << 8;
    const int nb = blockIdx.z;

    // staging: thread t covers row rA (+64 for 2nd issue), global chunk g.
    // phys slot s of row r holds global k-chunk s^(r&7) (XOR on the GLOBAL
    // address so the wave-uniform-base LDS layout stays linear).
    const int rA = t >> 3;              // 0..63
    const int g  = (t & 7) ^ (rA & 7);
    const unsigned short* Ag = w3b + (size_t)(m0 + rA) * CC + g * 8;
    const unsigned short* Bg = xT + (size_t)nb * PP * CC + (size_t)(p0 + rA) * CC + g * 8;
    const int ldsw = wave << 10;        // wave*1024 (HW adds lane*16)

    // ds_read bases: wave's A half = wave>>2 ; B half = (wave&3)>>1,
    // B sub-offset (wave&1)*64 rows. Row within a 16-row frag = lane&15.
    const char* Abase = sm + ((wave >> 2) << 14) + (lane & 15) * 128;
    const char* Bbase = sm + 65536 + (((wave & 3) >> 1) << 14) + ((wave & 1) << 13) + (lane & 15) * 128;

    // 16x16x32 frag: lane reads k-chunk (ks*4 + lane>>4), phys = logical ^ (row&7);
    // row&7 == lane&7 for all frags. ck1 = ck0 ^ 0x40.
    const int ck0 = (((lane >> 4) ^ swz) << 4);
    const int ck1 = ck0 ^ 0x40;

    f32x4 acc[8][4];
#pragma unroll
    for (int i = 0; i < 8; ++i)
#pragma unroll
        for (int j = 0; j < 4; ++j)
            acc[i][j] = (f32x4){0.f, 0.f, 0.f, 0.f};

    bfrag a0k0, a0k1, a1k0, a1k1, a2k0, a2k1, a3k0, a3k1;   // A mi0-3
    bfrag a4k0, a4k1, a5k0, a5k1, a6k0, a6k1, a7k0, a7k1;   // A mi4-7
    bfrag bn0k0, bn0k1, bn1k0, bn1k1;                       // B ni0-1
    bfrag bn2k0, bn2k1, bn3k0, bn3k1;                       // B ni2-3

#define STG(SB, DO, kt, h) do { \
    const unsigned short* _s = (SB) + (size_t)(h) * 128 * CC + (size_t)(kt) * 64; \
    char* _d = sm + (DO) + (((kt) & 1) << 15) + ((h) << 14) + ldsw; \
    __builtin_amdgcn_global_load_lds(AS1(_s), AS3(_d), 16, 0, 0); \
    __builtin_amdgcn_global_load_lds(AS1(_s + 64 * CC), AS3(_d + 8192), 16, 0, 0); \
} while (0)

#define LD(dst, BASE, OFF) dst = *(const bfrag*)((BASE) + (OFF))
#define Q(I, J, A_, B_) acc[I][J] = __builtin_amdgcn_mfma_f32_16x16x32_bf16(A_, B_, acc[I][J], 0, 0, 0)
#define BARR __builtin_amdgcn_s_barrier()
#define SB0  __builtin_amdgcn_sched_barrier(0)
#define WLG(N) do { asm volatile("s_waitcnt lgkmcnt(" #N ")" ::: "memory"); __builtin_amdgcn_sched_barrier(0); } while (0)
#define WVM(N) asm volatile("s_waitcnt vmcnt(" #N ")" ::: "memory")
#define PRI(x) __builtin_amdgcn_s_setprio(x)

// Entry invariant (tile kt, buffer P=kt&1): a0-3(kt) + bn01(kt) reads in
// flight (issued prev tile p3/p4); VM outstanding = B(kt+1)'s 4 loads.
#define TILE(P, NP, kt, IA, IB, IR, V2, V0, WL3) do { \
    /* p1 */ \
    SB0; \
    LD(bn2k0, Bbase, ((P) << 15) + (2 << 11) + ck0); LD(bn2k1, Bbase, ((P) << 15) + (2 << 11) + ck1); \
    LD(bn3k0, Bbase, ((P) << 15) + (3 << 11) + ck0); LD(bn3k1, Bbase, ((P) << 15) + (3 << 11) + ck1); \
    if (IA) STG(Ag, 0, (kt) + 1, 0); \
    SB0; BARR; WLG(4); PRI(1); \
    Q(0, 0, a0k0, bn0k0); Q(1, 0, a1k0, bn0k0); Q(2, 0, a2k0, bn0k0); Q(3, 0, a3k0, bn0k0); \
    Q(0, 1, a0k0, bn1k0); Q(1, 1, a1k0, bn1k0); Q(2, 1, a2k0, bn1k0); Q(3, 1, a3k0, bn1k0); \
    Q(0, 0, a0k1, bn0k1); Q(1, 0, a1k1, bn0k1); Q(2, 0, a2k1, bn0k1); Q(3, 0, a3k1, bn0k1); \
    Q(0, 1, a0k1, bn1k1); Q(1, 1, a1k1, bn1k1); Q(2, 1, a2k1, bn1k1); Q(3, 1, a3k1, bn1k1); \
    PRI(0); BARR; \
    /* p2 */ \
    SB0; \
    LD(a4k0, Abase, ((P) << 15) + (4 << 11) + ck0); LD(a4k1, Abase, ((P) << 15) + (4 << 11) + ck1); \
    LD(a5k0, Abase, ((P) << 15) + (5 << 11) + ck0); LD(a5k1, Abase, ((P) << 15) + (5 << 11) + ck1); \
    LD(a6k0, Abase, ((P) << 15) + (6 << 11) + ck0); LD(a6k1, Abase, ((P) << 15) + (6 << 11) + ck1); \
    LD(a7k0, Abase, ((P) << 15) + (7 << 11) + ck0); LD(a7k1, Abase, ((P) << 15) + (7 << 11) + ck1); \
    if (IA) STG(Ag, 0, (kt) + 1, 1); \
    SB0; BARR; WLG(8); PRI(1); \
    Q(0, 2, a0k0, bn2k0); Q(1, 2, a1k0, bn2k0); Q(2, 2, a2k0, bn2k0); Q(3, 2, a3k0, bn2k0); \
    Q(0, 3, a0k0, bn3k0); Q(1, 3, a1k0, bn3k0); Q(2, 3, a2k0, bn3k0); Q(3, 3, a3k0, bn3k0); \
    Q(0, 2, a0k1, bn2k1); Q(1, 2, a1k1, bn2k1); Q(2, 2, a2k1, bn2k1); Q(3, 2, a3k1, bn2k1); \
    Q(0, 3, a0k1, bn3k1); Q(1, 3, a1k1, bn3k1); Q(2, 3, a2k1, bn3k1); Q(3, 3, a3k1, bn3k1); \
    PRI(0); BARR; \
    /* p3 */ \
    SB0; \
    if (IB) STG(Bg, 65536, (kt) + 2, 0); \
    if (V2) WVM(2); \
    if (V0) WVM(0); \
    BARR; SB0; \
    if (IR) { \
        LD(a0k0, Abase, ((NP) << 15) + (0 << 11) + ck0); LD(a0k1, Abase, ((NP) << 15) + (0 << 11) + ck1); \
        LD(a1k0, Abase, ((NP) << 15) + (1 << 11) + ck0); LD(a1k1, Abase, ((NP) << 15) + (1 << 11) + ck1); \
        LD(a2k0, Abase, ((NP) << 15) + (2 << 11) + ck0); LD(a2k1, Abase, ((NP) << 15) + (2 << 11) + ck1); \
        LD(a3k0, Abase, ((NP) << 15) + (3 << 11) + ck0); LD(a3k1, Abase, ((NP) << 15) + (3 << 11) + ck1); \
    } \
    SB0; WLG(WL3); PRI(1); \
    Q(4, 2, a4k0, bn2k0); Q(5, 2, a5k0, bn2k0); Q(6, 2, a6k0, bn2k0); Q(7, 2, a7k0, bn2k0); \
    Q(4, 3, a4k0, bn3k0); Q(5, 3, a5k0, bn3k0); Q(6, 3, a6k0, bn3k0); Q(7, 3, a7k0, bn3k0); \
    Q(4, 2, a4k1, bn2k1); Q(5, 2, a5k1, bn2k1); Q(6, 2, a6k1, bn2k1); Q(7, 2, a7k1, bn2k1); \
    Q(4, 3, a4k1, bn3k1); Q(5, 3, a5k1, bn3k1); Q(6, 3, a6k1, bn3k1); Q(7, 3, a7k1, bn3k1); \
    PRI(0); BARR; \
    /* p4 */ \
    SB0; \
    if (IB) STG(Bg, 65536, (kt) + 2, 1); \
    SB0; BARR; SB0; PRI(1); \
    Q(4, 0, a4k0, bn0k0); Q(5, 0, a5k0, bn0k0); Q(6, 0, a6k0, bn0k0); Q(7, 0, a7k0, bn0k0); \
    Q(4, 1, a4k0, bn1k0); Q(5, 1, a5k0, bn1k0); Q(6, 1, a6k0, bn1k0); Q(7, 1, a7k0, bn1k0); \
    Q(4, 0, a4k1, bn0k1); Q(5, 0, a5k1, bn0k1); Q(6, 0, a6k1, bn0k1); Q(7, 0, a7k1, bn0k1); \
    Q(4, 1, a4k1, bn1k1); Q(5, 1, a5k1, bn1k1); Q(6, 1, a6k1, bn1k1); Q(7, 1, a7k1, bn1k1); \
    PRI(0); \
    if (IR) { \
        LD(bn0k0, Bbase, ((NP) << 15) + (0 << 11) + ck0); LD(bn0k1, Bbase, ((NP) << 15) + (0 << 11) + ck1); \
        LD(bn1k0, Bbase, ((NP) << 15) + (1 << 11) + ck0); LD(bn1k1, Bbase, ((NP) << 15) + (1 << 11) + ck1); \
    } \
    SB0; BARR; \
} while (0)

    // prologue: A(0),B(0) -> buf0; B(1) -> buf1. vmcnt(4) retires A(0)+B(0)
    // (leaves B(1) = entry invariant), barrier (cross-wave landing), then
    // issue tile0's first-cluster reads (a0-3(0) + bn01(0)) = the phase-lead
    // state p1's WLG(4) expects.
    STG(Ag, 0, 0, 0); STG(Ag, 0, 0, 1);
    STG(Bg, 65536, 0, 0); STG(Bg, 65536, 0, 1);
    STG(Bg, 65536, 1, 0); STG(Bg, 65536, 1, 1);
    WVM(4);
    BARR; SB0;
    LD(a0k0, Abase, (0 << 11) + ck0); LD(a0k1, Abase, (0 << 11) + ck1);
    LD(a1k0, Abase, (1 << 11) + ck0); LD(a1k1, Abase, (1 << 11) + ck1);
    LD(a2k0, Abase, (2 << 11) + ck0); LD(a2k1, Abase, (2 << 11) + ck1);
    LD(a3k0, Abase, (3 << 11) + ck0); LD(a3k1, Abase, (3 << 11) + ck1);
    LD(bn0k0, Bbase, (0 << 11) + ck0); LD(bn0k1, Bbase, (0 << 11) + ck1);
    LD(bn1k0, Bbase, (1 << 11) + ck0); LD(bn1k1, Bbase, (1 << 11) + ck1);
    SB0;

#pragma unroll 1
    for (int kt = 0; kt < 30; kt += 2) {
        TILE(0, 1, kt,     1, 1, 1, 1, 0, 8);
        TILE(1, 0, kt + 1, 1, 1, 1, 1, 0, 8);
    }
    // tile 30: stages A(31); no B(32); vmcnt(0) at p3 (epilogue drain — no
    // future loads exist) before the a0-3(31)/bn01(31) phase-lead reads.
    TILE(0, 1, 30, 1, 0, 1, 0, 1, 8);
    // tile 31: pure compute; p3 gate = WLG(0) (drain a4-7, no younger reads).
    TILE(1, 0, 31, 0, 0, 0, 0, 0, 0);

#undef TILE
#undef STG
#undef LD
#undef Q
#undef BARR
#undef SB0
#undef WLG
#undef WVM
#undef PRI

    // epilogue: 16x16 C/D layout: row = (lane>>4)*4 + reg, col = lane&15
    const int wr = (wave >> 2) << 7;
    const int wc = (wave & 3) << 6;
    const int q4 = (lane >> 4) << 2;
    const int cl = lane & 15;
    float* outn = out + (size_t)nb * CC * PP;
#pragma unroll
    for (int mi = 0; mi < 8; ++mi) {
#pragma unroll
        for (int r = 0; r < 4; ++r) {
            const int o = m0 + wr + mi * 16 + q4 + r;
            const float bias = b3[o];
            float* orow = outn + (size_t)o * PP + p0 + wc + cl;
#pragma unroll
            for (int ni = 0; ni < 4; ++ni) {
                float v = acc[mi][ni][r] + bias;
                orow[ni * 16] = v > 0.f ? v : 0.f;
            }
        }
    }
}

// ---------------- guarded attention fallback (alpha != 0 only) ----------------
__global__ void fb_e12(const float* __restrict__ x,
                       const float* __restrict__ w1, const float* __restrict__ b1,
                       const float* __restrict__ w2, const float* __restrict__ b2,
                       const float* __restrict__ alpha,
                       float* __restrict__ e1, float* __restrict__ e2) {
    if (alpha[0] == 0.f) return;
    const size_t total = (size_t)NB * DD * PP;
    for (size_t idx = (size_t)blockIdx.x * blockDim.x + threadIdx.x; idx < total;
         idx += (size_t)gridDim.x * blockDim.x) {
        int p = (int)(idx % PP);
        size_t nd = idx / PP;
        int d = (int)(nd % DD);
        int n = (int)(nd / DD);
        const float* xn = x + (size_t)n * CC * PP + p;
        float s1 = b1[d], s2 = b2[d];
        for (int c = 0; c < CC; ++c) {
            float xv = xn[(size_t)c * PP];
            s1 += w1[(size_t)d * CC + c] * xv;
            s2 += w2[(size_t)d * CC + c] * xv;
        }
        e1[idx] = fmaxf(s1, 0.f);
        e2[idx] = fmaxf(s2, 0.f);
    }
}

__global__ void fb_attn(const float* __restrict__ x,
                        const float* __restrict__ e1, const float* __restrict__ e2,
                        const float* __restrict__ alpha,
                        float* __restrict__ out) {
    const float a = alpha[0];
    if (a == 0.f) return;   // uniform early-exit (no barrier crossed)
    __shared__ float s[PP];
    __shared__ float e1i[DD];
    __shared__ float red[256];
    const int t = threadIdx.x;
    for (int ii = blockIdx.x; ii < NB * PP; ii += gridDim.x) {
        const int n = ii >> 12;
        const int i = ii & (PP - 1);
        const float* e1n = e1 + (size_t)n * DD * PP;
        const float* e2n = e2 + (size_t)n * DD * PP;
        if (t < DD) e1i[t] = e1n[(size_t)t * PP + i];
        __syncthreads();
        for (int j = t; j < PP; j += 256) {
            float acc = 0.f;
            for (int d = 0; d < DD; ++d) acc += e1i[d] * e2n[(size_t)d * PP + j];
            s[j] = acc;
        }
        __syncthreads();
        float m = -INFINITY;
        for (int j = t; j < PP; j += 256) m = fmaxf(m, s[j]);
        red[t] = m; __syncthreads();
        for (int o = 128; o > 0; o >>= 1) { if (t < o) red[t] = fmaxf(red[t], red[t + o]); __syncthreads(); }
        m = red[0]; __syncthreads();
        float l = 0.f;
        for (int j = t; j < PP; j += 256) { float e = __expf(s[j] - m); s[j] = e; l += e; }
        red[t] = l; __syncthreads();
        for (int o = 128; o > 0; o >>= 1) { if (t < o) red[t] += red[t + o]; __syncthreads(); }
        l = red[0]; __syncthreads();
        const float inv = a / l;
        const float* xn = x + (size_t)n * CC * PP;
        float* on = out + (size_t)n * CC * PP;
        for (int c = t; c < CC; c += 256) {
            const float* xr = xn + (size_t)c * PP;
            float acc = 0.f;
            for (int j = 0; j < PP; ++j) acc += s[j] * xr[j];
            on[(size_t)c * PP + i] += inv * acc;
        }
        __syncthreads();
    }
}

extern "C" void kernel_launch(void* const* d_in, const int* in_sizes, int n_in,
                              void* d_out, int out_size, void* d_ws, size_t ws_size,
                              hipStream_t stream) {
    (void)in_sizes; (void)n_in; (void)out_size; (void)ws_size;
    const float* x     = (const float*)d_in[0];
    const float* w1    = (const float*)d_in[1];
    const float* b1    = (const float*)d_in[2];
    const float* w2    = (const float*)d_in[3];
    const float* b2    = (const float*)d_in[4];
    const float* w3    = (const float*)d_in[5];
    const float* b3    = (const float*)d_in[6];
    const float* alpha = (const float*)d_in[7];
    float* out = (float*)d_out;

    unsigned short* xT  = (unsigned short*)d_ws;
    unsigned short* w3b = (unsigned short*)((char*)d_ws + (size_t)NB * PP * CC * 2);
    float* e1 = (float*)d_ws;
    float* e2 = e1 + (size_t)NB * DD * PP;

    prep<<<dim3(PP / 64, CC / 64, NB + 1), dim3(256), 0, stream>>>(x, xT, w3, w3b);
    gemm_assembly<<<dim3(PP / 256, CC / 256, NB), dim3(512), 0, stream>>>(w3b, xT, b3, out);
    fb_e12<<<dim3(512), dim3(256), 0, stream>>>(x, w1, b1, w2, b2, alpha, e1, e2);
    fb_attn<<<dim3(1024), dim3(256), 0, stream>>>(x, e1, e2, alpha, out);
}